// Round 15
// baseline (271.951 us; speedup 1.0000x reference)
//
#include <hip/hip_runtime.h>
#include <hip/hip_bf16.h>

#define N_NODES 20000
#define N_EDGES 320000
#define BATCH 2
#define IN_DIM 32
#define HID 64
#define HEADS 4
#define OUT_DIM 8
#define ROWS (N_NODES * BATCH) /* 40000 */
#define SLOPE 0.2f

typedef __hip_bfloat16 bf16;
typedef short v8s __attribute__((ext_vector_type(8)));
typedef float v4f __attribute__((ext_vector_type(4)));

// ---- workspace layout (float slots) ----
#define WS_XB32     0         /* 20000*64 u32: packed bf16 (b0,b1) x table */
#define WS_AGGXB    1280000   /* 20000*256 u32: packed normalized head-aggregates */
#define WS_EL       6400000   /* 160,000 */
#define WS_ER       6560000   /* 160,000 */
#define WS_DEG      6720000   /* 20,032 ints */
#define WS_ROWSTART 6740032   /* 20,032 ints (20001 used) */
#define WS_CUR      6760064   /* 20,032 ints */
#define WS_CSRC     6780096   /* 320,000 ints */
#define WS_WGBPK    7100096   /* 16384 u16 */
#define WS_WRESBPK  7108288   /* 4096 u16 */
#define WS_WX8PK    7110336   /* 1024 u16 */
#define WS_WENCBPK  7110848   /* 2048 u16 */
#define WS_WDECBPK  7111872   /* 1024 u16 */
#define WS_BGM      7112384   /* 64 floats */
#define WS_END      7112448   /* ~28.4 MB */

__device__ __forceinline__ float us2f(unsigned short u) {
    union { unsigned int i; float f; } z; z.i = ((unsigned int)u) << 16; return z.f;
}
__device__ __forceinline__ unsigned short f2us(float f) {
    bf16 b = __float2bfloat16(f);
    return *(unsigned short*)&b;
}
__device__ __forceinline__ float ld(const void* p, int i, int isbf) {
    if (isbf) return us2f(((const unsigned short*)p)[i]);
    return ((const float*)p)[i];
}
__device__ __forceinline__ float lrexp(float v) {
    v = v > 0.f ? v : SLOPE * v;
    return __expf(fminf(v, 60.f));
}

// Inline bf16-vs-fp32 sniffer (see R2/R9 notes): 64 even 16-bit halves of h per wave.
__device__ __forceinline__ int sniff64(const void* h) {
    const unsigned short* u = (const unsigned short*)h;
    int lane = threadIdx.x & 63;
    unsigned short v = u[2 * lane];
    int ef = (v >> 7) & 0xFF;
    unsigned long long m = __ballot(ef >= 100 && ef <= 150);
    return __popcll(m) >= 48;
}

// Pack all B-operands into MFMA-fragment-native layout (one 16B load per frag).
// Blocks 18..37 additionally zero the deg array (replaces a hipMemsetAsync dispatch).
__global__ __launch_bounds__(256) void k_prep(const void* __restrict__ h,
                                              const void* __restrict__ Wg,
                                              const void* __restrict__ al,
                                              const void* __restrict__ ar,
                                              const void* __restrict__ Wr,
                                              const void* __restrict__ We,
                                              const void* __restrict__ Wd,
                                              const void* __restrict__ bg,
                                              unsigned short* __restrict__ WgBpk,
                                              unsigned short* __restrict__ WresBpk,
                                              unsigned short* __restrict__ Wx8pk,
                                              unsigned short* __restrict__ WencBpk,
                                              unsigned short* __restrict__ WdecBpk,
                                              float* __restrict__ bgm,
                                              int* __restrict__ deg) {
    int t = threadIdx.x, b = blockIdx.x;
    if (b >= 18) {
        int base = (b - 18) * 1024 + t * 4;
#pragma unroll
        for (int i = 0; i < 4; i++)
            if (base + i < 20032) deg[base + i] = 0;
        return;
    }
    const int isbf = sniff64(h);
    if (b < 16) {
#pragma unroll
        for (int q = 0; q < 4; q++) {
            int idx = b * 1024 + q * 256 + t;
            int j = idx & 7, m16 = (idx >> 3) & 15, quad = (idx >> 7) & 3;
            int ks = (idx >> 9) & 1, ct = (idx >> 10) & 3, hh = (idx >> 12) & 3;
            int k = ks * 32 + quad * 8 + j;
            int c = hh * 64 + ct * 16 + m16;
            WgBpk[idx] = f2us(ld(Wg, k * 256 + c, isbf));
        }
    } else if (b == 16) {
#pragma unroll
        for (int q = 0; q < 4; q++) {
            int idx = q * 256 + t;
            int j = idx & 7, m16 = (idx >> 3) & 15, quad = (idx >> 7) & 3;
            int ks = (idx >> 9) & 1;
            int k = ks * 32 + quad * 8 + j;
            float v = 0.f;
            if (m16 < 8) {
                int hh = m16 & 3, lr = m16 >> 2;
                const void* a = lr ? ar : al;
                for (int d = 0; d < 64; d++)
                    v += ld(Wg, k * 256 + hh * 64 + d, isbf) * ld(a, hh * 64 + d, isbf);
            }
            Wx8pk[idx] = f2us(v);
        }
#pragma unroll
        for (int q = 0; q < 8; q++) {
            int idx = q * 256 + t;
            int j = idx & 7, m16 = (idx >> 3) & 15, quad = (idx >> 7) & 3, ct = idx >> 9;
            int k = quad * 8 + j;
            WencBpk[idx] = f2us(ld(We, k * 64 + ct * 16 + m16, isbf));
        }
#pragma unroll
        for (int q = 0; q < 4; q++) {
            int idx = q * 256 + t;
            int j = idx & 7, m16 = (idx >> 3) & 15, quad = (idx >> 7) & 3;
            int ks = (idx >> 9) & 1;
            int k = ks * 32 + quad * 8 + j;
            WdecBpk[idx] = (m16 < 8) ? f2us(ld(Wd, k * 8 + m16, isbf)) : (unsigned short)0;
        }
        if (t < 64) {
            float s = 0.f;
            for (int hh = 0; hh < 4; hh++) s += ld(bg, hh * 64 + t, isbf);
            bgm[t] = 0.25f * s;
        }
    } else {
#pragma unroll
        for (int q = 0; q < 16; q++) {
            int idx = q * 256 + t;
            int j = idx & 7, m16 = (idx >> 3) & 15, quad = (idx >> 7) & 3;
            int ks = (idx >> 9) & 1, ct = (idx >> 10) & 3;
            int k = ks * 32 + quad * 8 + j;
            WresBpk[idx] = f2us(ld(Wr, k * 64 + ct * 16 + m16, isbf));
        }
    }
}

// ---- CSR build ----
__global__ __launch_bounds__(256) void k_hist(const int* __restrict__ dst, int* __restrict__ deg) {
    int e = blockIdx.x * 256 + threadIdx.x;
    if (e < N_EDGES) atomicAdd(&deg[dst[e]], 1);
}

__global__ __launch_bounds__(1024) void k_scan(const int* __restrict__ deg,
                                               int* __restrict__ rowstart,
                                               int* __restrict__ cursor) {
    __shared__ int ssum[1024];
    int t = threadIdx.x;
    int base = t * 20;
    int local[20];
    int s = 0;
#pragma unroll
    for (int i = 0; i < 20; i++) {
        int v = (base + i < N_NODES) ? deg[base + i] : 0;
        local[i] = s;
        s += v;
    }
    ssum[t] = s;
    __syncthreads();
    for (int off = 1; off < 1024; off <<= 1) {
        int v = (t >= off) ? ssum[t - off] : 0;
        __syncthreads();
        if (t >= off) ssum[t] += v;
        __syncthreads();
    }
    int prev = (t == 0) ? 0 : ssum[t - 1];
#pragma unroll
    for (int i = 0; i < 20; i++) {
        if (base + i < N_NODES) {
            int v = prev + local[i];
            rowstart[base + i] = v;
            cursor[base + i] = v;
        }
    }
    if (t == 1023) rowstart[N_NODES] = ssum[1023];
}

__global__ __launch_bounds__(256) void k_scatter(const int* __restrict__ src,
                                                 const int* __restrict__ dst,
                                                 int* __restrict__ cursor,
                                                 int* __restrict__ csrc) {
    int e = blockIdx.x * 256 + threadIdx.x;
    if (e >= N_EDGES) return;
    int pos = atomicAdd(&cursor[dst[e]], 1);
    csrc[pos] = src[e];
}

// Fused encoder: xb32 (packed bf16 batch-pair x) + el/er, via one K=32 MFMA step.
// 64-row blocks (R12-proven): wave w = rows w*16..+15.
__global__ __launch_bounds__(256) void k_enc2(const void* __restrict__ h,
                                              const unsigned short* __restrict__ WencBpk,
                                              const void* __restrict__ benc,
                                              const unsigned short* __restrict__ Wx8pk,
                                              unsigned int* __restrict__ xb32,
                                              float* __restrict__ el,
                                              float* __restrict__ er) {
    const int isbf = sniff64(h);
    __shared__ unsigned short sXb[64 * 64];
    int t = threadIdx.x;
    int w = t >> 6, lane = t & 63, quad = lane >> 4, m16 = lane & 15;
    int row0 = blockIdx.x * 64;
    int grow = row0 + w * 16 + m16;
    int n = grow >> 1, b = grow & 1;

    v8s Af;
    size_t hb = (size_t)(b * N_NODES + n) * IN_DIM + quad * 8;
    if (isbf) {
        Af = *(const v8s*)((const unsigned short*)h + hb);
    } else {
        const float4* hp = (const float4*)((const float*)h + hb);
        float4 xa = hp[0], xbv = hp[1];
        Af[0] = (short)f2us(xa.x);  Af[1] = (short)f2us(xa.y);
        Af[2] = (short)f2us(xa.z);  Af[3] = (short)f2us(xa.w);
        Af[4] = (short)f2us(xbv.x); Af[5] = (short)f2us(xbv.y);
        Af[6] = (short)f2us(xbv.z); Af[7] = (short)f2us(xbv.w);
    }

    v4f acc[4];
#pragma unroll
    for (int ct = 0; ct < 4; ct++) {
        v8s Bf = *(const v8s*)(WencBpk + ((ct << 9) | (quad << 7) | (m16 << 3)));
        acc[ct] = __builtin_amdgcn_mfma_f32_16x16x32_bf16(Af, Bf, (v4f)(0.f), 0, 0, 0);
    }

#pragma unroll
    for (int ct = 0; ct < 4; ct++) {
        int col = ct * 16 + m16;
        float bv = ld(benc, col, isbf);
        float vr[4];
        int rloc0 = w * 16 + quad * 4;
#pragma unroll
        for (int r = 0; r < 4; r++) {
            vr[r] = acc[ct][r] + bv;
            sXb[(rloc0 + r) * 64 + col] = f2us(vr[r]);
        }
        int nd0 = (row0 + rloc0) >> 1;
        xb32[(size_t)nd0 * 64 + col] =
            (unsigned int)f2us(vr[0]) | ((unsigned int)f2us(vr[1]) << 16);
        xb32[(size_t)(nd0 + 1) * 64 + col] =
            (unsigned int)f2us(vr[2]) | ((unsigned int)f2us(vr[3]) << 16);
    }
    __syncthreads();
    v4f e8 = (v4f)(0.f);
#pragma unroll
    for (int ks = 0; ks < 2; ks++) {
        v8s Af2 = *(const v8s*)(sXb + (w * 16 + m16) * 64 + ks * 32 + quad * 8);
        v8s Bf = *(const v8s*)(Wx8pk + (((ks * 4 + quad) << 7) + (m16 << 3)));
        e8 = __builtin_amdgcn_mfma_f32_16x16x32_bf16(Af2, Bf, e8, 0, 0, 0);
    }
    if (m16 < 8) {
#pragma unroll
        for (int r = 0; r < 4; r++) {
            int gr = row0 + w * 16 + quad * 4 + r;
            float v = e8[r];
            if (m16 < 4) el[gr * 4 + m16] = v;
            else         er[gr * 4 + (m16 - 4)] = v;
        }
    }
}

// Edge phase as MFMA, TWO WAVES per node (col-tile halves) for 2x TLP:
// wave (n, tlh) handles col tiles tl = tlh*2 + {0,1}. Weights (A-frag) and accW
// are duplicated per wave (cheap: 8 csrc + 8 masked el gathers); xb32 gathers halve.
__global__ __launch_bounds__(256) void k_agg(const int* __restrict__ rowstart,
                                             const int* __restrict__ csrc,
                                             const float* __restrict__ el,
                                             const float* __restrict__ er,
                                             const unsigned int* __restrict__ xb32,
                                             unsigned int* __restrict__ aggxb) {
    int t = threadIdx.x;
    int wid = blockIdx.x * 4 + (t >> 6);
    int n = wid >> 1;
    int tlh = wid & 1;
    int lane = t & 63;
    int quad = lane >> 4, m16 = lane & 15;
    int i8 = m16 & 7;
    float erv = er[n * 8 + i8];
    int beg = rowstart[n], end = rowstart[n + 1];

    v4f accB0[2], accB1[2], accW;
#pragma unroll
    for (int tl2 = 0; tl2 < 2; tl2++) { accB0[tl2] = (v4f)(0.f); accB1[tl2] = (v4f)(0.f); }
    accW = (v4f)(0.f);
    v8s Bones;
#pragma unroll
    for (int j = 0; j < 8; j++) Bones[j] = (short)0x3F80;  // bf16 1.0

    for (int p0 = beg; p0 < end; p0 += 32) {
        int rem = end - p0;
        int s[8];
#pragma unroll
        for (int j = 0; j < 8; j++) {
            int idx = p0 + quad * 8 + j;
            s[j] = csrc[idx < end ? idx : beg];
        }
        v8s Af;
#pragma unroll
        for (int j = 0; j < 8; j++) {
            float wv = (quad * 8 + j < rem) ? lrexp(el[s[j] * 8 + i8] + erv) : 0.f;
            Af[j] = (m16 < 8) ? (short)f2us(wv) : (short)0;
        }
        accW = __builtin_amdgcn_mfma_f32_16x16x32_bf16(Af, Bones, accW, 0, 0, 0);
#pragma unroll
        for (int tl2 = 0; tl2 < 2; tl2++) {
            int tl = tlh * 2 + tl2;
            v8s B0, B1;
#pragma unroll
            for (int j = 0; j < 8; j++) {
                unsigned int q = xb32[(size_t)s[j] * 64 + tl * 16 + m16];
                B0[j] = (short)(q & 0xffffu);
                B1[j] = (short)(q >> 16);
            }
            accB0[tl2] = __builtin_amdgcn_mfma_f32_16x16x32_bf16(Af, B0, accB0[tl2], 0, 0, 0);
            accB1[tl2] = __builtin_amdgcn_mfma_f32_16x16x32_bf16(Af, B1, accB1[tl2], 0, 0, 0);
        }
    }

    int has = (end > beg);
#pragma unroll
    for (int tl2 = 0; tl2 < 2; tl2++) {
        int tl = tlh * 2 + tl2;
#pragma unroll
        for (int r = 0; r < 4; r++) {
            float mine = (quad == 0) ? accB0[tl2][r] : accB1[tl2][r];
            float wss = accW[r];
            float v = (has && wss > 0.f) ? mine / (4.f * wss) : 0.f;
            float v1 = __shfl(v, lane + 16);
            if (quad == 0) {
                aggxb[(size_t)n * 256 + r * 64 + tl * 16 + m16] =
                    (unsigned int)f2us(v) | ((unsigned int)f2us(v1) << 16);
            }
        }
    }
}

// Fused update (R12-proven 64-row blocks): v = elu( sum_h(Ah/4 @ Wg_h) + bgm + x @ W_res + b_res ).
// emit=1: write next xb32 + el/er.  emit=0: fused decoder -> d_out.
__global__ __launch_bounds__(256) void k_update(const void* __restrict__ h,
                                                const unsigned int* __restrict__ aggxb,
                                                const unsigned short* __restrict__ WgBpk,
                                                const unsigned short* __restrict__ WresBpk,
                                                const unsigned short* __restrict__ Wx8pk,
                                                const unsigned short* __restrict__ WdecBpk,
                                                const void* __restrict__ br,
                                                const void* __restrict__ bd,
                                                const float* __restrict__ bgm,
                                                unsigned int* __restrict__ xb32,
                                                float* __restrict__ el,
                                                float* __restrict__ er,
                                                void* __restrict__ out,
                                                int emit) {
    const int isbf = sniff64(h);
    __shared__ unsigned short sXb[64 * 64];
    int t = threadIdx.x;
    int w = t >> 6, lane = t & 63, quad = lane >> 4, m16 = lane & 15;
    int row0 = blockIdx.x * 64;
    int grow = row0 + w * 16 + m16;
    int nd = grow >> 1;
    unsigned sh = (grow & 1) * 16;

    v4f acc[4];
#pragma unroll
    for (int ct = 0; ct < 4; ct++) acc[ct] = (v4f)(0.f);

#pragma unroll
    for (int hh = 0; hh < 4; hh++) {
#pragma unroll
        for (int ks = 0; ks < 2; ks++) {
            const uint4* ap = (const uint4*)(aggxb + (size_t)nd * 256 + hh * 64 + ks * 32 + quad * 8);
            uint4 qa = ap[0], qb = ap[1];
            v8s Af;
            Af[0] = (short)((qa.x >> sh) & 0xffffu);
            Af[1] = (short)((qa.y >> sh) & 0xffffu);
            Af[2] = (short)((qa.z >> sh) & 0xffffu);
            Af[3] = (short)((qa.w >> sh) & 0xffffu);
            Af[4] = (short)((qb.x >> sh) & 0xffffu);
            Af[5] = (short)((qb.y >> sh) & 0xffffu);
            Af[6] = (short)((qb.z >> sh) & 0xffffu);
            Af[7] = (short)((qb.w >> sh) & 0xffffu);
#pragma unroll
            for (int ct = 0; ct < 4; ct++) {
                v8s Bf = *(const v8s*)(WgBpk + ((hh << 12) | (ct << 10) | (ks << 9) | (quad << 7) | (m16 << 3)));
                acc[ct] = __builtin_amdgcn_mfma_f32_16x16x32_bf16(Af, Bf, acc[ct], 0, 0, 0);
            }
        }
    }
#pragma unroll
    for (int ks = 0; ks < 2; ks++) {
        const uint4* xp = (const uint4*)(xb32 + (size_t)nd * 64 + ks * 32 + quad * 8);
        uint4 qa = xp[0], qb = xp[1];
        v8s Af;
        Af[0] = (short)((qa.x >> sh) & 0xffffu);
        Af[1] = (short)((qa.y >> sh) & 0xffffu);
        Af[2] = (short)((qa.z >> sh) & 0xffffu);
        Af[3] = (short)((qa.w >> sh) & 0xffffu);
        Af[4] = (short)((qb.x >> sh) & 0xffffu);
        Af[5] = (short)((qb.y >> sh) & 0xffffu);
        Af[6] = (short)((qb.z >> sh) & 0xffffu);
        Af[7] = (short)((qb.w >> sh) & 0xffffu);
#pragma unroll
        for (int ct = 0; ct < 4; ct++) {
            v8s Bf = *(const v8s*)(WresBpk + ((ct << 10) | (ks << 9) | (quad << 7) | (m16 << 3)));
            acc[ct] = __builtin_amdgcn_mfma_f32_16x16x32_bf16(Af, Bf, acc[ct], 0, 0, 0);
        }
    }

    if (emit) __syncthreads();   // WAR: all xb32 reads complete before rewrite

#pragma unroll
    for (int ct = 0; ct < 4; ct++) {
        int col = ct * 16 + m16;
        float bv = ld(br, col, isbf) + bgm[col];
        float vr[4];
        int rloc0 = w * 16 + quad * 4;
#pragma unroll
        for (int r = 0; r < 4; r++) {
            float v = acc[ct][r] + bv;
            v = v > 0.f ? v : expm1f(v);
            vr[r] = v;
            sXb[(rloc0 + r) * 64 + col] = f2us(v);
        }
        if (emit) {
            int nd0 = (row0 + rloc0) >> 1;
            xb32[(size_t)nd0 * 64 + col] =
                (unsigned int)f2us(vr[0]) | ((unsigned int)f2us(vr[1]) << 16);
            xb32[(size_t)(nd0 + 1) * 64 + col] =
                (unsigned int)f2us(vr[2]) | ((unsigned int)f2us(vr[3]) << 16);
        }
    }
    __syncthreads();
    if (emit) {
        v4f e8 = (v4f)(0.f);
#pragma unroll
        for (int ks = 0; ks < 2; ks++) {
            v8s Af = *(const v8s*)(sXb + (w * 16 + m16) * 64 + ks * 32 + quad * 8);
            v8s Bf = *(const v8s*)(Wx8pk + (((ks * 4 + quad) << 7) + (m16 << 3)));
            e8 = __builtin_amdgcn_mfma_f32_16x16x32_bf16(Af, Bf, e8, 0, 0, 0);
        }
        if (m16 < 8) {
#pragma unroll
            for (int r = 0; r < 4; r++) {
                int gr = row0 + w * 16 + quad * 4 + r;
                float v = e8[r];
                if (m16 < 4) el[gr * 4 + m16] = v;
                else         er[gr * 4 + (m16 - 4)] = v;
            }
        }
    } else {
        v4f o8 = (v4f)(0.f);
#pragma unroll
        for (int ks = 0; ks < 2; ks++) {
            v8s Af = *(const v8s*)(sXb + (w * 16 + m16) * 64 + ks * 32 + quad * 8);
            v8s Bf = *(const v8s*)(WdecBpk + ((ks << 9) | (quad << 7) | (m16 << 3)));
            o8 = __builtin_amdgcn_mfma_f32_16x16x32_bf16(Af, Bf, o8, 0, 0, 0);
        }
        if (m16 < 8) {
            float bv = ld(bd, m16, isbf);
#pragma unroll
            for (int r = 0; r < 4; r++) {
                int gr = row0 + w * 16 + quad * 4 + r;
                int nn = gr >> 1, bb = gr & 1;
                size_t oi = (size_t)(bb * N_NODES + nn) * OUT_DIM + m16;
                float v = o8[r] + bv;
                if (isbf) ((unsigned short*)out)[oi] = f2us(v);
                else      ((float*)out)[oi] = v;
            }
        }
    }
}

extern "C" void kernel_launch(void* const* d_in, const int* in_sizes, int n_in,
                              void* d_out, int out_size, void* d_ws, size_t ws_size,
                              hipStream_t stream) {
    const void* h     = d_in[0];
    const int*  ei    = (const int*)d_in[1];
    const void* W_enc = d_in[2];
    const void* b_enc = d_in[3];
    const void* W_gat = d_in[4];
    const void* a_l   = d_in[5];
    const void* a_r   = d_in[6];
    const void* b_gat = d_in[7];
    const void* W_res = d_in[8];
    const void* b_res = d_in[9];
    const void* W_dec = d_in[10];
    const void* b_dec = d_in[11];

    float* ws = (float*)d_ws;
    unsigned int* xb32  = (unsigned int*)(ws + WS_XB32);
    unsigned int* aggxb = (unsigned int*)(ws + WS_AGGXB);
    float* el       = ws + WS_EL;
    float* er       = ws + WS_ER;
    int*   deg      = (int*)(ws + WS_DEG);
    int*   rowstart = (int*)(ws + WS_ROWSTART);
    int*   cursor   = (int*)(ws + WS_CUR);
    int*   csrc     = (int*)(ws + WS_CSRC);
    unsigned short* WgBpk   = (unsigned short*)(ws + WS_WGBPK);
    unsigned short* WresBpk = (unsigned short*)(ws + WS_WRESBPK);
    unsigned short* Wx8pk   = (unsigned short*)(ws + WS_WX8PK);
    unsigned short* WencBpk = (unsigned short*)(ws + WS_WENCBPK);
    unsigned short* WdecBpk = (unsigned short*)(ws + WS_WDECBPK);
    float* bgm      = ws + WS_BGM;

    const int* src = ei;
    const int* dst = ei + N_EDGES;

    k_prep<<<38, 256, 0, stream>>>(h, W_gat, a_l, a_r, W_res, W_enc, W_dec, b_gat,
                                   WgBpk, WresBpk, Wx8pk, WencBpk, WdecBpk, bgm, deg);
    k_hist<<<(N_EDGES + 255) / 256, 256, 0, stream>>>(dst, deg);
    k_scan<<<1, 1024, 0, stream>>>(deg, rowstart, cursor);
    k_scatter<<<(N_EDGES + 255) / 256, 256, 0, stream>>>(src, dst, cursor, csrc);

    k_enc2<<<ROWS / 64, 256, 0, stream>>>(h, WencBpk, b_enc, Wx8pk, xb32, el, er);

    for (int r = 0; r < 2; r++) {
        k_agg<<<N_NODES / 2, 256, 0, stream>>>(rowstart, csrc, el, er, xb32, aggxb);
        k_update<<<ROWS / 64, 256, 0, stream>>>(h, aggxb, WgBpk, WresBpk, Wx8pk, WdecBpk,
                                                b_res, b_dec, bgm, xb32, el, er, d_out,
                                                r == 0 ? 1 : 0);
    }
}

// Round 16
// 263.318 us; speedup vs baseline: 1.0328x; 1.0328x over previous
//
#include <hip/hip_runtime.h>
#include <hip/hip_bf16.h>

#define N_NODES 20000
#define N_EDGES 320000
#define BATCH 2
#define IN_DIM 32
#define HID 64
#define HEADS 4
#define OUT_DIM 8
#define ROWS (N_NODES * BATCH) /* 40000 */
#define SLOPE 0.2f

typedef __hip_bfloat16 bf16;
typedef short v8s __attribute__((ext_vector_type(8)));
typedef float v4f __attribute__((ext_vector_type(4)));

// ---- workspace layout (float slots) ----
#define WS_XB32     0         /* 20000*64 u32: packed bf16 (b0,b1) x table */
#define WS_AGGXB    1280000   /* 20000*256 u32: packed normalized head-aggregates */
#define WS_EL       6400000   /* 160,000 */
#define WS_ER       6560000   /* 160,000 */
#define WS_DEG      6720000   /* 20,032 ints */
#define WS_ROWSTART 6740032   /* 20,032 ints (20001 used) */
#define WS_CUR      6760064   /* 20,032 ints */
#define WS_CSRC     6780096   /* 320,000 ints */
#define WS_WGBPK    7100096   /* 16384 u16 */
#define WS_WRESBPK  7108288   /* 4096 u16 */
#define WS_WX8PK    7110336   /* 1024 u16 */
#define WS_WENCBPK  7110848   /* 2048 u16 */
#define WS_WDECBPK  7111872   /* 1024 u16 */
#define WS_BGM      7112384   /* 64 floats */
#define WS_END      7112448   /* ~28.4 MB */

__device__ __forceinline__ float us2f(unsigned short u) {
    union { unsigned int i; float f; } z; z.i = ((unsigned int)u) << 16; return z.f;
}
__device__ __forceinline__ unsigned short f2us(float f) {
    bf16 b = __float2bfloat16(f);
    return *(unsigned short*)&b;
}
__device__ __forceinline__ float ld(const void* p, int i, int isbf) {
    if (isbf) return us2f(((const unsigned short*)p)[i]);
    return ((const float*)p)[i];
}
__device__ __forceinline__ float lrexp(float v) {
    v = v > 0.f ? v : SLOPE * v;
    return __expf(fminf(v, 60.f));
}

// Inline bf16-vs-fp32 sniffer (see R2/R9 notes): 64 even 16-bit halves of h per wave.
__device__ __forceinline__ int sniff64(const void* h) {
    const unsigned short* u = (const unsigned short*)h;
    int lane = threadIdx.x & 63;
    unsigned short v = u[2 * lane];
    int ef = (v >> 7) & 0xFF;
    unsigned long long m = __ballot(ef >= 100 && ef <= 150);
    return __popcll(m) >= 48;
}

// Pack all B-operands into MFMA-fragment-native layout (one 16B load per frag).
// Blocks 18..37 additionally zero the deg array (replaces a hipMemsetAsync dispatch).
__global__ __launch_bounds__(256) void k_prep(const void* __restrict__ h,
                                              const void* __restrict__ Wg,
                                              const void* __restrict__ al,
                                              const void* __restrict__ ar,
                                              const void* __restrict__ Wr,
                                              const void* __restrict__ We,
                                              const void* __restrict__ Wd,
                                              const void* __restrict__ bg,
                                              unsigned short* __restrict__ WgBpk,
                                              unsigned short* __restrict__ WresBpk,
                                              unsigned short* __restrict__ Wx8pk,
                                              unsigned short* __restrict__ WencBpk,
                                              unsigned short* __restrict__ WdecBpk,
                                              float* __restrict__ bgm,
                                              int* __restrict__ deg) {
    int t = threadIdx.x, b = blockIdx.x;
    if (b >= 18) {
        int base = (b - 18) * 1024 + t * 4;
#pragma unroll
        for (int i = 0; i < 4; i++)
            if (base + i < 20032) deg[base + i] = 0;
        return;
    }
    const int isbf = sniff64(h);
    if (b < 16) {
#pragma unroll
        for (int q = 0; q < 4; q++) {
            int idx = b * 1024 + q * 256 + t;
            int j = idx & 7, m16 = (idx >> 3) & 15, quad = (idx >> 7) & 3;
            int ks = (idx >> 9) & 1, ct = (idx >> 10) & 3, hh = (idx >> 12) & 3;
            int k = ks * 32 + quad * 8 + j;
            int c = hh * 64 + ct * 16 + m16;
            WgBpk[idx] = f2us(ld(Wg, k * 256 + c, isbf));
        }
    } else if (b == 16) {
#pragma unroll
        for (int q = 0; q < 4; q++) {
            int idx = q * 256 + t;
            int j = idx & 7, m16 = (idx >> 3) & 15, quad = (idx >> 7) & 3;
            int ks = (idx >> 9) & 1;
            int k = ks * 32 + quad * 8 + j;
            float v = 0.f;
            if (m16 < 8) {
                int hh = m16 & 3, lr = m16 >> 2;
                const void* a = lr ? ar : al;
                for (int d = 0; d < 64; d++)
                    v += ld(Wg, k * 256 + hh * 64 + d, isbf) * ld(a, hh * 64 + d, isbf);
            }
            Wx8pk[idx] = f2us(v);
        }
#pragma unroll
        for (int q = 0; q < 8; q++) {
            int idx = q * 256 + t;
            int j = idx & 7, m16 = (idx >> 3) & 15, quad = (idx >> 7) & 3, ct = idx >> 9;
            int k = quad * 8 + j;
            WencBpk[idx] = f2us(ld(We, k * 64 + ct * 16 + m16, isbf));
        }
#pragma unroll
        for (int q = 0; q < 4; q++) {
            int idx = q * 256 + t;
            int j = idx & 7, m16 = (idx >> 3) & 15, quad = (idx >> 7) & 3;
            int ks = (idx >> 9) & 1;
            int k = ks * 32 + quad * 8 + j;
            WdecBpk[idx] = (m16 < 8) ? f2us(ld(Wd, k * 8 + m16, isbf)) : (unsigned short)0;
        }
        if (t < 64) {
            float s = 0.f;
            for (int hh = 0; hh < 4; hh++) s += ld(bg, hh * 64 + t, isbf);
            bgm[t] = 0.25f * s;
        }
    } else {
#pragma unroll
        for (int q = 0; q < 16; q++) {
            int idx = q * 256 + t;
            int j = idx & 7, m16 = (idx >> 3) & 15, quad = (idx >> 7) & 3;
            int ks = (idx >> 9) & 1, ct = (idx >> 10) & 3;
            int k = ks * 32 + quad * 8 + j;
            WresBpk[idx] = f2us(ld(Wr, k * 64 + ct * 16 + m16, isbf));
        }
    }
}

// ---- CSR build ----
__global__ __launch_bounds__(256) void k_hist(const int* __restrict__ dst, int* __restrict__ deg) {
    int e = blockIdx.x * 256 + threadIdx.x;
    if (e < N_EDGES) atomicAdd(&deg[dst[e]], 1);
}

__global__ __launch_bounds__(1024) void k_scan(const int* __restrict__ deg,
                                               int* __restrict__ rowstart,
                                               int* __restrict__ cursor) {
    __shared__ int ssum[1024];
    int t = threadIdx.x;
    int base = t * 20;
    int local[20];
    int s = 0;
#pragma unroll
    for (int i = 0; i < 20; i++) {
        int v = (base + i < N_NODES) ? deg[base + i] : 0;
        local[i] = s;
        s += v;
    }
    ssum[t] = s;
    __syncthreads();
    for (int off = 1; off < 1024; off <<= 1) {
        int v = (t >= off) ? ssum[t - off] : 0;
        __syncthreads();
        if (t >= off) ssum[t] += v;
        __syncthreads();
    }
    int prev = (t == 0) ? 0 : ssum[t - 1];
#pragma unroll
    for (int i = 0; i < 20; i++) {
        if (base + i < N_NODES) {
            int v = prev + local[i];
            rowstart[base + i] = v;
            cursor[base + i] = v;
        }
    }
    if (t == 1023) rowstart[N_NODES] = ssum[1023];
}

__global__ __launch_bounds__(256) void k_scatter(const int* __restrict__ src,
                                                 const int* __restrict__ dst,
                                                 int* __restrict__ cursor,
                                                 int* __restrict__ csrc) {
    int e = blockIdx.x * 256 + threadIdx.x;
    if (e >= N_EDGES) return;
    int pos = atomicAdd(&cursor[dst[e]], 1);
    csrc[pos] = src[e];
}

// Fused encoder: xb32 (packed bf16 batch-pair x) + el/er, via one K=32 MFMA step.
// 64-row blocks (R12-proven): wave w = rows w*16..+15.
__global__ __launch_bounds__(256) void k_enc2(const void* __restrict__ h,
                                              const unsigned short* __restrict__ WencBpk,
                                              const void* __restrict__ benc,
                                              const unsigned short* __restrict__ Wx8pk,
                                              unsigned int* __restrict__ xb32,
                                              float* __restrict__ el,
                                              float* __restrict__ er) {
    const int isbf = sniff64(h);
    __shared__ unsigned short sXb[64 * 64];
    int t = threadIdx.x;
    int w = t >> 6, lane = t & 63, quad = lane >> 4, m16 = lane & 15;
    int row0 = blockIdx.x * 64;
    int grow = row0 + w * 16 + m16;
    int n = grow >> 1, b = grow & 1;

    v8s Af;
    size_t hb = (size_t)(b * N_NODES + n) * IN_DIM + quad * 8;
    if (isbf) {
        Af = *(const v8s*)((const unsigned short*)h + hb);
    } else {
        const float4* hp = (const float4*)((const float*)h + hb);
        float4 xa = hp[0], xbv = hp[1];
        Af[0] = (short)f2us(xa.x);  Af[1] = (short)f2us(xa.y);
        Af[2] = (short)f2us(xa.z);  Af[3] = (short)f2us(xa.w);
        Af[4] = (short)f2us(xbv.x); Af[5] = (short)f2us(xbv.y);
        Af[6] = (short)f2us(xbv.z); Af[7] = (short)f2us(xbv.w);
    }

    v4f acc[4];
#pragma unroll
    for (int ct = 0; ct < 4; ct++) {
        v8s Bf = *(const v8s*)(WencBpk + ((ct << 9) | (quad << 7) | (m16 << 3)));
        acc[ct] = __builtin_amdgcn_mfma_f32_16x16x32_bf16(Af, Bf, (v4f)(0.f), 0, 0, 0);
    }

#pragma unroll
    for (int ct = 0; ct < 4; ct++) {
        int col = ct * 16 + m16;
        float bv = ld(benc, col, isbf);
        float vr[4];
        int rloc0 = w * 16 + quad * 4;
#pragma unroll
        for (int r = 0; r < 4; r++) {
            vr[r] = acc[ct][r] + bv;
            sXb[(rloc0 + r) * 64 + col] = f2us(vr[r]);
        }
        int nd0 = (row0 + rloc0) >> 1;
        xb32[(size_t)nd0 * 64 + col] =
            (unsigned int)f2us(vr[0]) | ((unsigned int)f2us(vr[1]) << 16);
        xb32[(size_t)(nd0 + 1) * 64 + col] =
            (unsigned int)f2us(vr[2]) | ((unsigned int)f2us(vr[3]) << 16);
    }
    __syncthreads();
    v4f e8 = (v4f)(0.f);
#pragma unroll
    for (int ks = 0; ks < 2; ks++) {
        v8s Af2 = *(const v8s*)(sXb + (w * 16 + m16) * 64 + ks * 32 + quad * 8);
        v8s Bf = *(const v8s*)(Wx8pk + (((ks * 4 + quad) << 7) + (m16 << 3)));
        e8 = __builtin_amdgcn_mfma_f32_16x16x32_bf16(Af2, Bf, e8, 0, 0, 0);
    }
    if (m16 < 8) {
#pragma unroll
        for (int r = 0; r < 4; r++) {
            int gr = row0 + w * 16 + quad * 4 + r;
            float v = e8[r];
            if (m16 < 4) el[gr * 4 + m16] = v;
            else         er[gr * 4 + (m16 - 4)] = v;
        }
    }
}

// Edge phase as MFMA (R12-proven): one wave per node. Per 32-edge chunk:
//   A[m=combo(i8) via m16][k=edge via quad*8+j] = bf16 weight (rows 8..15 = 0)
//   B0/B1[k=edge][n=col tile*16+m16] = bf16 x (batch 0 / 1), from packed xb32
//   accW = A x ones  -> row-sums (wss) in C-layout, in-lane
__global__ __launch_bounds__(256) void k_agg(const int* __restrict__ rowstart,
                                             const int* __restrict__ csrc,
                                             const float* __restrict__ el,
                                             const float* __restrict__ er,
                                             const unsigned int* __restrict__ xb32,
                                             unsigned int* __restrict__ aggxb) {
    int t = threadIdx.x;
    int n = blockIdx.x * 4 + (t >> 6);
    int lane = t & 63;
    int quad = lane >> 4, m16 = lane & 15;
    int i8 = m16 & 7;
    float erv = er[n * 8 + i8];
    int beg = rowstart[n], end = rowstart[n + 1];

    v4f accB0[4], accB1[4], accW;
#pragma unroll
    for (int tl = 0; tl < 4; tl++) { accB0[tl] = (v4f)(0.f); accB1[tl] = (v4f)(0.f); }
    accW = (v4f)(0.f);
    v8s Bones;
#pragma unroll
    for (int j = 0; j < 8; j++) Bones[j] = (short)0x3F80;  // bf16 1.0

    for (int p0 = beg; p0 < end; p0 += 32) {
        int rem = end - p0;
        int s[8];
#pragma unroll
        for (int j = 0; j < 8; j++) {
            int idx = p0 + quad * 8 + j;
            s[j] = csrc[idx < end ? idx : beg];
        }
        v8s Af;
#pragma unroll
        for (int j = 0; j < 8; j++) {
            float wv = (quad * 8 + j < rem) ? lrexp(el[s[j] * 8 + i8] + erv) : 0.f;
            Af[j] = (m16 < 8) ? (short)f2us(wv) : (short)0;
        }
        accW = __builtin_amdgcn_mfma_f32_16x16x32_bf16(Af, Bones, accW, 0, 0, 0);
#pragma unroll
        for (int tl = 0; tl < 4; tl++) {
            v8s B0, B1;
#pragma unroll
            for (int j = 0; j < 8; j++) {
                unsigned int q = xb32[(size_t)s[j] * 64 + tl * 16 + m16];
                B0[j] = (short)(q & 0xffffu);
                B1[j] = (short)(q >> 16);
            }
            accB0[tl] = __builtin_amdgcn_mfma_f32_16x16x32_bf16(Af, B0, accB0[tl], 0, 0, 0);
            accB1[tl] = __builtin_amdgcn_mfma_f32_16x16x32_bf16(Af, B1, accB1[tl], 0, 0, 0);
        }
    }

    int has = (end > beg);
#pragma unroll
    for (int tl = 0; tl < 4; tl++) {
#pragma unroll
        for (int r = 0; r < 4; r++) {
            float mine = (quad == 0) ? accB0[tl][r] : accB1[tl][r];
            float wss = accW[r];
            float v = (has && wss > 0.f) ? mine / (4.f * wss) : 0.f;
            float v1 = __shfl(v, lane + 16);
            if (quad == 0) {
                aggxb[(size_t)n * 256 + r * 64 + tl * 16 + m16] =
                    (unsigned int)f2us(v) | ((unsigned int)f2us(v1) << 16);
            }
        }
    }
}

// Fused update (R12-proven 64-row blocks): v = elu( sum_h(Ah/4 @ Wg_h) + bgm + x @ W_res + b_res ).
// emit=1: write next xb32 + el/er.  emit=0: fused decoder -> d_out.
__global__ __launch_bounds__(256) void k_update(const void* __restrict__ h,
                                                const unsigned int* __restrict__ aggxb,
                                                const unsigned short* __restrict__ WgBpk,
                                                const unsigned short* __restrict__ WresBpk,
                                                const unsigned short* __restrict__ Wx8pk,
                                                const unsigned short* __restrict__ WdecBpk,
                                                const void* __restrict__ br,
                                                const void* __restrict__ bd,
                                                const float* __restrict__ bgm,
                                                unsigned int* __restrict__ xb32,
                                                float* __restrict__ el,
                                                float* __restrict__ er,
                                                void* __restrict__ out,
                                                int emit) {
    const int isbf = sniff64(h);
    __shared__ unsigned short sXb[64 * 64];
    int t = threadIdx.x;
    int w = t >> 6, lane = t & 63, quad = lane >> 4, m16 = lane & 15;
    int row0 = blockIdx.x * 64;
    int grow = row0 + w * 16 + m16;
    int nd = grow >> 1;
    unsigned sh = (grow & 1) * 16;

    v4f acc[4];
#pragma unroll
    for (int ct = 0; ct < 4; ct++) acc[ct] = (v4f)(0.f);

#pragma unroll
    for (int hh = 0; hh < 4; hh++) {
#pragma unroll
        for (int ks = 0; ks < 2; ks++) {
            const uint4* ap = (const uint4*)(aggxb + (size_t)nd * 256 + hh * 64 + ks * 32 + quad * 8);
            uint4 qa = ap[0], qb = ap[1];
            v8s Af;
            Af[0] = (short)((qa.x >> sh) & 0xffffu);
            Af[1] = (short)((qa.y >> sh) & 0xffffu);
            Af[2] = (short)((qa.z >> sh) & 0xffffu);
            Af[3] = (short)((qa.w >> sh) & 0xffffu);
            Af[4] = (short)((qb.x >> sh) & 0xffffu);
            Af[5] = (short)((qb.y >> sh) & 0xffffu);
            Af[6] = (short)((qb.z >> sh) & 0xffffu);
            Af[7] = (short)((qb.w >> sh) & 0xffffu);
#pragma unroll
            for (int ct = 0; ct < 4; ct++) {
                v8s Bf = *(const v8s*)(WgBpk + ((hh << 12) | (ct << 10) | (ks << 9) | (quad << 7) | (m16 << 3)));
                acc[ct] = __builtin_amdgcn_mfma_f32_16x16x32_bf16(Af, Bf, acc[ct], 0, 0, 0);
            }
        }
    }
#pragma unroll
    for (int ks = 0; ks < 2; ks++) {
        const uint4* xp = (const uint4*)(xb32 + (size_t)nd * 64 + ks * 32 + quad * 8);
        uint4 qa = xp[0], qb = xp[1];
        v8s Af;
        Af[0] = (short)((qa.x >> sh) & 0xffffu);
        Af[1] = (short)((qa.y >> sh) & 0xffffu);
        Af[2] = (short)((qa.z >> sh) & 0xffffu);
        Af[3] = (short)((qa.w >> sh) & 0xffffu);
        Af[4] = (short)((qb.x >> sh) & 0xffffu);
        Af[5] = (short)((qb.y >> sh) & 0xffffu);
        Af[6] = (short)((qb.z >> sh) & 0xffffu);
        Af[7] = (short)((qb.w >> sh) & 0xffffu);
#pragma unroll
        for (int ct = 0; ct < 4; ct++) {
            v8s Bf = *(const v8s*)(WresBpk + ((ct << 10) | (ks << 9) | (quad << 7) | (m16 << 3)));
            acc[ct] = __builtin_amdgcn_mfma_f32_16x16x32_bf16(Af, Bf, acc[ct], 0, 0, 0);
        }
    }

    if (emit) __syncthreads();   // WAR: all xb32 reads complete before rewrite

#pragma unroll
    for (int ct = 0; ct < 4; ct++) {
        int col = ct * 16 + m16;
        float bv = ld(br, col, isbf) + bgm[col];
        float vr[4];
        int rloc0 = w * 16 + quad * 4;
#pragma unroll
        for (int r = 0; r < 4; r++) {
            float v = acc[ct][r] + bv;
            v = v > 0.f ? v : expm1f(v);
            vr[r] = v;
            sXb[(rloc0 + r) * 64 + col] = f2us(v);
        }
        if (emit) {
            int nd0 = (row0 + rloc0) >> 1;
            xb32[(size_t)nd0 * 64 + col] =
                (unsigned int)f2us(vr[0]) | ((unsigned int)f2us(vr[1]) << 16);
            xb32[(size_t)(nd0 + 1) * 64 + col] =
                (unsigned int)f2us(vr[2]) | ((unsigned int)f2us(vr[3]) << 16);
        }
    }
    __syncthreads();
    if (emit) {
        v4f e8 = (v4f)(0.f);
#pragma unroll
        for (int ks = 0; ks < 2; ks++) {
            v8s Af = *(const v8s*)(sXb + (w * 16 + m16) * 64 + ks * 32 + quad * 8);
            v8s Bf = *(const v8s*)(Wx8pk + (((ks * 4 + quad) << 7) + (m16 << 3)));
            e8 = __builtin_amdgcn_mfma_f32_16x16x32_bf16(Af, Bf, e8, 0, 0, 0);
        }
        if (m16 < 8) {
#pragma unroll
            for (int r = 0; r < 4; r++) {
                int gr = row0 + w * 16 + quad * 4 + r;
                float v = e8[r];
                if (m16 < 4) el[gr * 4 + m16] = v;
                else         er[gr * 4 + (m16 - 4)] = v;
            }
        }
    } else {
        v4f o8 = (v4f)(0.f);
#pragma unroll
        for (int ks = 0; ks < 2; ks++) {
            v8s Af = *(const v8s*)(sXb + (w * 16 + m16) * 64 + ks * 32 + quad * 8);
            v8s Bf = *(const v8s*)(WdecBpk + ((ks << 9) | (quad << 7) | (m16 << 3)));
            o8 = __builtin_amdgcn_mfma_f32_16x16x32_bf16(Af, Bf, o8, 0, 0, 0);
        }
        if (m16 < 8) {
            float bv = ld(bd, m16, isbf);
#pragma unroll
            for (int r = 0; r < 4; r++) {
                int gr = row0 + w * 16 + quad * 4 + r;
                int nn = gr >> 1, bb = gr & 1;
                size_t oi = (size_t)(bb * N_NODES + nn) * OUT_DIM + m16;
                float v = o8[r] + bv;
                if (isbf) ((unsigned short*)out)[oi] = f2us(v);
                else      ((float*)out)[oi] = v;
            }
        }
    }
}

extern "C" void kernel_launch(void* const* d_in, const int* in_sizes, int n_in,
                              void* d_out, int out_size, void* d_ws, size_t ws_size,
                              hipStream_t stream) {
    const void* h     = d_in[0];
    const int*  ei    = (const int*)d_in[1];
    const void* W_enc = d_in[2];
    const void* b_enc = d_in[3];
    const void* W_gat = d_in[4];
    const void* a_l   = d_in[5];
    const void* a_r   = d_in[6];
    const void* b_gat = d_in[7];
    const void* W_res = d_in[8];
    const void* b_res = d_in[9];
    const void* W_dec = d_in[10];
    const void* b_dec = d_in[11];

    float* ws = (float*)d_ws;
    unsigned int* xb32  = (unsigned int*)(ws + WS_XB32);
    unsigned int* aggxb = (unsigned int*)(ws + WS_AGGXB);
    float* el       = ws + WS_EL;
    float* er       = ws + WS_ER;
    int*   deg      = (int*)(ws + WS_DEG);
    int*   rowstart = (int*)(ws + WS_ROWSTART);
    int*   cursor   = (int*)(ws + WS_CUR);
    int*   csrc     = (int*)(ws + WS_CSRC);
    unsigned short* WgBpk   = (unsigned short*)(ws + WS_WGBPK);
    unsigned short* WresBpk = (unsigned short*)(ws + WS_WRESBPK);
    unsigned short* Wx8pk   = (unsigned short*)(ws + WS_WX8PK);
    unsigned short* WencBpk = (unsigned short*)(ws + WS_WENCBPK);
    unsigned short* WdecBpk = (unsigned short*)(ws + WS_WDECBPK);
    float* bgm      = ws + WS_BGM;

    const int* src = ei;
    const int* dst = ei + N_EDGES;

    k_prep<<<38, 256, 0, stream>>>(h, W_gat, a_l, a_r, W_res, W_enc, W_dec, b_gat,
                                   WgBpk, WresBpk, Wx8pk, WencBpk, WdecBpk, bgm, deg);
    k_hist<<<(N_EDGES + 255) / 256, 256, 0, stream>>>(dst, deg);
    k_scan<<<1, 1024, 0, stream>>>(deg, rowstart, cursor);
    k_scatter<<<(N_EDGES + 255) / 256, 256, 0, stream>>>(src, dst, cursor, csrc);

    k_enc2<<<ROWS / 64, 256, 0, stream>>>(h, WencBpk, b_enc, Wx8pk, xb32, el, er);

    for (int r = 0; r < 2; r++) {
        k_agg<<<N_NODES / 4, 256, 0, stream>>>(rowstart, csrc, el, er, xb32, aggxb);
        k_update<<<ROWS / 64, 256, 0, stream>>>(h, aggxb, WgBpk, WresBpk, Wx8pk, WdecBpk,
                                                b_res, b_dec, bgm, xb32, el, er, d_out,
                                                r == 0 ? 1 : 0);
    }
}